// Round 2
// baseline (145.515 us; speedup 1.0000x reference)
//
#include <hip/hip_runtime.h>
#include <stdint.h>

#define Bn 8
#define Nn 2000
#define Cc 81
#define META_STRIDE (12 + Cc)
#define MAXI 100
#define MINCONF 0.7f
#define NMSTHR 0.3f
#define NPAD 2048
#define NW 32   // 64-bit words per mask row (2048 bits)

// map float to monotonically ordered uint (descending float == descending uint)
__device__ __forceinline__ uint32_t ford(float f) {
    uint32_t u = __float_as_uint(f);
    return (u & 0x80000000u) ? ~u : (u | 0x80000000u);
}

// ---------------- Kernel 1: per-ROI argmax, delta apply, clip, sort key ----
__global__ void k_prep(const float* __restrict__ rois,
                       const float* __restrict__ probs,
                       const float* __restrict__ bbox,
                       const float* __restrict__ meta,
                       float* __restrict__ refined,
                       float* __restrict__ score,
                       int* __restrict__ cls,
                       unsigned long long* __restrict__ keys) {
    int t = blockIdx.x * blockDim.x + threadIdx.x;
    if (t >= Bn * Nn) return;
    int b = t / Nn;
    int i = t - b * Nn;

    const float* p = probs + (size_t)t * Cc;
    int   cbest = 0;
    float sbest = p[0];
    for (int c = 1; c < Cc; ++c) {
        float v = p[c];
        if (v > sbest) { sbest = v; cbest = c; }   // first max wins (strict >)
    }

    const float* d = bbox + ((size_t)t * Cc + (size_t)cbest) * 4;
    float dy = d[0] * 0.1f, dx = d[1] * 0.1f, dh = d[2] * 0.2f, dw = d[3] * 0.2f;

    const float* r = rois + (size_t)t * 4;
    float y1 = r[0], x1 = r[1], y2 = r[2], x2 = r[3];
    float h = y2 - y1, w = x2 - x1;
    float cy = y1 + 0.5f * h + dy * h;
    float cx = x1 + 0.5f * w + dx * w;
    h = h * expf(dh);
    w = w * expf(dw);
    float ny1 = cy - 0.5f * h, nx1 = cx - 0.5f * w;
    float ny2 = cy + 0.5f * h, nx2 = cx + 0.5f * w;

    // window = (meta[b,7:11] - [0,0,1,1]) / ([h,w,h,w]-1), image shape from meta row 0
    float sy = meta[4] - 1.0f, sx = meta[5] - 1.0f;
    const float* mb = meta + (size_t)b * META_STRIDE;
    float wy1 = mb[7] / sy;
    float wx1 = mb[8] / sx;
    float wy2 = (mb[9]  - 1.0f) / sy;
    float wx2 = (mb[10] - 1.0f) / sx;

    ny1 = fminf(fmaxf(ny1, wy1), wy2);
    nx1 = fminf(fmaxf(nx1, wx1), wx2);
    ny2 = fminf(fmaxf(ny2, wy1), wy2);
    nx2 = fminf(fmaxf(nx2, wx1), wx2);

    refined[4 * t + 0] = ny1;
    refined[4 * t + 1] = nx1;
    refined[4 * t + 2] = ny2;
    refined[4 * t + 3] = nx2;
    score[t] = sbest;
    cls[t]   = cbest;

    bool valid = (cbest > 0) && (sbest >= MINCONF);
    float ks = valid ? sbest : -1.0f;
    keys[t] = ((unsigned long long)ford(ks) << 32) |
              (unsigned long long)(0xFFFFFFFFu - (uint32_t)i);
}

// ---------------- Kernel 2: per-batch bitonic sort (desc), V, sorted boxes --
__global__ void __launch_bounds__(1024, 1)
k_sort(const unsigned long long* __restrict__ keys,
       const float* __restrict__ refined,
       const int* __restrict__ cls,
       uint32_t* __restrict__ sidx,
       float* __restrict__ sbox,
       int* __restrict__ Vout) {
    __shared__ unsigned long long sk[NPAD];
    __shared__ int sV;
    int b = blockIdx.x, tid = threadIdx.x;

    const unsigned long long* kb = keys + (size_t)b * Nn;
    for (int t = tid; t < NPAD; t += 1024)
        sk[t] = (t < Nn) ? kb[t] : 0ull;      // pads sort to the very end
    if (tid == 0) sV = 0;
    __syncthreads();

    for (int k = 2; k <= NPAD; k <<= 1) {
        for (int j = k >> 1; j > 0; j >>= 1) {
            for (int t = tid; t < NPAD; t += 1024) {
                int ixj = t ^ j;
                if (ixj > t) {
                    unsigned long long a = sk[t], c = sk[ixj];
                    bool desc = ((t & k) == 0);
                    if (desc ? (a < c) : (a > c)) { sk[t] = c; sk[ixj] = a; }
                }
            }
            __syncthreads();
        }
    }

    // valid entries (top bit set: score>=0.7>0) form a prefix; find its length
    for (int t = tid; t < Nn; t += 1024) {
        bool v0 = (sk[t] >> 63) != 0ull;
        bool v1 = (t + 1 < Nn) ? ((sk[t + 1] >> 63) != 0ull) : false;
        if (v0 && !v1) sV = t + 1;            // single boundary -> single writer
    }
    __syncthreads();
    if (tid == 0) Vout[b] = sV;

    for (int t = tid; t < Nn; t += 1024) {
        uint32_t oi = 0xFFFFFFFFu - (uint32_t)(sk[t] & 0xFFFFFFFFull);
        sidx[b * Nn + t] = oi;
        int gi = b * Nn + (int)oi;
        float off = 4.0f * (float)cls[gi];    // CLASS_OFFSET * class_id
        sbox[(size_t)(b * Nn + t) * 4 + 0] = refined[gi * 4 + 0] + off;
        sbox[(size_t)(b * Nn + t) * 4 + 1] = refined[gi * 4 + 1] + off;
        sbox[(size_t)(b * Nn + t) * 4 + 2] = refined[gi * 4 + 2] + off;
        sbox[(size_t)(b * Nn + t) * 4 + 3] = refined[gi * 4 + 3] + off;
    }
}

// ---------------- Kernel 3: IoU suppression bitmask, one wave per row -------
__global__ void k_iou(const float* __restrict__ sbox,
                      const int* __restrict__ Vbuf,
                      unsigned long long* __restrict__ mask) {
    int gt   = blockIdx.x * blockDim.x + threadIdx.x;
    int wid  = gt >> 6;
    int lane = threadIdx.x & 63;
    if (wid >= Bn * Nn) return;
    int b = wid / Nn, i = wid - b * Nn;
    int V = Vbuf[b];
    if (i >= V) return;

    const float* bb = sbox + (size_t)(b * Nn + i) * 4;
    float y1 = bb[0], x1 = bb[1], y2 = bb[2], x2 = bb[3];
    float ar = (y2 - y1) * (x2 - x1);

    unsigned long long* row = mask + ((size_t)(b * Nn) + (size_t)i) * NW;
    int w0 = i >> 6, wlast = (V - 1) >> 6;
    for (int w = w0; w <= wlast; ++w) {
        int j = (w << 6) + lane;
        bool sup = false;
        if (j > i && j < V) {
            const float* cb = sbox + (size_t)(b * Nn + j) * 4;
            float oy1 = cb[0], ox1 = cb[1], oy2 = cb[2], ox2 = cb[3];
            float a2 = (oy2 - oy1) * (ox2 - ox1);
            float iy = fmaxf(0.0f, fminf(y2, oy2) - fmaxf(y1, oy1));
            float ix = fmaxf(0.0f, fminf(x2, ox2) - fmaxf(x1, ox1));
            float inter = iy * ix;
            float iou = inter / (ar + a2 - inter + 1e-12f);
            sup = iou > NMSTHR;
        }
        unsigned long long ball = __ballot(sup);
        if (lane == 0) row[w] = ball;
    }
}

// ---------------- Kernel 4: sequential greedy scan + cap + emit, 1 wave/batch
__global__ void k_scan(const unsigned long long* __restrict__ mask,
                       const int* __restrict__ Vbuf,
                       const uint32_t* __restrict__ sidx,
                       const float* __restrict__ refined,
                       const float* __restrict__ score,
                       const int* __restrict__ cls,
                       float* __restrict__ out) {
    int b = blockIdx.x, lane = threadIdx.x;   // 64 threads = 1 wave
    volatile __shared__ unsigned long long rem[NW];
    volatile __shared__ int nout;
    __shared__ int cc[Cc];                    // touched only by lane 0

    if (lane < NW) rem[lane] = 0ull;
    for (int c = lane; c < Cc; c += 64) cc[c] = 0;
    if (lane == 0) nout = 0;

    float* ob = out + (size_t)b * MAXI * 6;
    for (int t = lane; t < MAXI * 6; t += 64) ob[t] = 0.0f;

    int V = Vbuf[b];
    for (int i = 0; i < V; ++i) {
        unsigned long long wbits = rem[i >> 6];
        if ((wbits >> (i & 63)) & 1ull) continue;      // suppressed (uniform)

        // kept: merge its suppression row (lanes 0..31 own one word each)
        const unsigned long long* row = mask + ((size_t)(b * Nn) + (size_t)i) * NW;
        int w0 = i >> 6, wl = (V - 1) >> 6;
        if (lane >= w0 && lane <= wl) rem[lane] |= row[lane];

        if (lane == 0) {
            uint32_t oi = sidx[b * Nn + i];
            int gi = b * Nn + (int)oi;
            int c  = cls[gi];
            int cnt = cc[c];
            cc[c] = cnt + 1;                           // counts post-NMS kept
            if (cnt < MAXI) {                          // per-class rank cap
                int slot = nout;
                if (slot < MAXI) {
                    nout = slot + 1;
                    float* orow = ob + slot * 6;
                    orow[0] = refined[gi * 4 + 0];
                    orow[1] = refined[gi * 4 + 1];
                    orow[2] = refined[gi * 4 + 2];
                    orow[3] = refined[gi * 4 + 3];
                    orow[4] = (float)c;
                    orow[5] = score[gi];
                }
            }
        }
        if (nout >= MAXI) break;                       // uniform (volatile LDS)
    }
}

// ---------------- launch ----------------------------------------------------
extern "C" void kernel_launch(void* const* d_in, const int* in_sizes, int n_in,
                              void* d_out, int out_size, void* d_ws, size_t ws_size,
                              hipStream_t stream) {
    const float* rois  = (const float*)d_in[0];
    const float* probs = (const float*)d_in[1];
    const float* bbox  = (const float*)d_in[2];
    const float* meta  = (const float*)d_in[3];
    float* out = (float*)d_out;

    const int BN = Bn * Nn;
    char* ws = (char*)d_ws;
    size_t off = 0;
    auto alloc = [&](size_t bytes) {
        void* p = ws + off;
        off += (bytes + 255) & ~(size_t)255;
        return p;
    };
    float*              refined = (float*)              alloc((size_t)BN * 4 * sizeof(float));
    float*              score   = (float*)              alloc((size_t)BN * sizeof(float));
    int*                cls     = (int*)                alloc((size_t)BN * sizeof(int));
    unsigned long long* keys    = (unsigned long long*) alloc((size_t)BN * sizeof(unsigned long long));
    uint32_t*           sidx    = (uint32_t*)           alloc((size_t)BN * sizeof(uint32_t));
    float*              sbox    = (float*)              alloc((size_t)BN * 4 * sizeof(float));
    int*                Vbuf    = (int*)                alloc((size_t)Bn * sizeof(int));
    unsigned long long* mask    = (unsigned long long*) alloc((size_t)BN * NW * sizeof(unsigned long long));
    (void)ws_size; (void)in_sizes; (void)n_in; (void)out_size;

    k_prep<<<(BN + 255) / 256, 256, 0, stream>>>(rois, probs, bbox, meta,
                                                 refined, score, cls, keys);
    k_sort<<<Bn, 1024, 0, stream>>>(keys, refined, cls, sidx, sbox, Vbuf);
    k_iou<<<(BN * 64 + 255) / 256, 256, 0, stream>>>(sbox, Vbuf, mask);
    k_scan<<<Bn, 64, 0, stream>>>(mask, Vbuf, sidx, refined, score, cls, out);
}

// Round 4
// 68.685 us; speedup vs baseline: 2.1186x; 2.1186x over previous
//
#include <hip/hip_runtime.h>
#include <stdint.h>

#define Bn 8
#define Nn 2000
#define Cc 81
#define META_STRIDE (12 + Cc)
#define MAXI 100
#define MINCONF 0.7f
#define NMSTHR 0.3f
#define NPAD 2048
#define NW 32   // 64-bit words per mask row (2048 bits)

// map float to monotonically ordered uint (descending float == descending uint)
__device__ __forceinline__ uint32_t ford(float f) {
    uint32_t u = __float_as_uint(f);
    return (u & 0x80000000u) ? ~u : (u | 0x80000000u);
}

// ---------------- Kernel 1: per-ROI argmax, delta apply, clip, sort key ----
__global__ void k_prep(const float* __restrict__ rois,
                       const float* __restrict__ probs,
                       const float* __restrict__ bbox,
                       const float* __restrict__ meta,
                       float* __restrict__ refined,
                       float* __restrict__ score,
                       int* __restrict__ cls,
                       unsigned long long* __restrict__ keys) {
    int t = blockIdx.x * blockDim.x + threadIdx.x;
    if (t >= Bn * Nn) return;
    int b = t / Nn;
    int i = t - b * Nn;

    const float* p = probs + (size_t)t * Cc;
    int   cbest = 0;
    float sbest = p[0];
    for (int c = 1; c < Cc; ++c) {
        float v = p[c];
        if (v > sbest) { sbest = v; cbest = c; }   // first max wins (strict >)
    }

    const float* d = bbox + ((size_t)t * Cc + (size_t)cbest) * 4;
    float dy = d[0] * 0.1f, dx = d[1] * 0.1f, dh = d[2] * 0.2f, dw = d[3] * 0.2f;

    const float* r = rois + (size_t)t * 4;
    float y1 = r[0], x1 = r[1], y2 = r[2], x2 = r[3];
    float h = y2 - y1, w = x2 - x1;
    float cy = y1 + 0.5f * h + dy * h;
    float cx = x1 + 0.5f * w + dx * w;
    h = h * expf(dh);
    w = w * expf(dw);
    float ny1 = cy - 0.5f * h, nx1 = cx - 0.5f * w;
    float ny2 = cy + 0.5f * h, nx2 = cx + 0.5f * w;

    // window = (meta[b,7:11] - [0,0,1,1]) / ([h,w,h,w]-1), image shape from meta row 0
    float sy = meta[4] - 1.0f, sx = meta[5] - 1.0f;
    const float* mb = meta + (size_t)b * META_STRIDE;
    float wy1 = mb[7] / sy;
    float wx1 = mb[8] / sx;
    float wy2 = (mb[9]  - 1.0f) / sy;
    float wx2 = (mb[10] - 1.0f) / sx;

    ny1 = fminf(fmaxf(ny1, wy1), wy2);
    nx1 = fminf(fmaxf(nx1, wx1), wx2);
    ny2 = fminf(fmaxf(ny2, wy1), wy2);
    nx2 = fminf(fmaxf(nx2, wx1), wx2);

    refined[4 * t + 0] = ny1;
    refined[4 * t + 1] = nx1;
    refined[4 * t + 2] = ny2;
    refined[4 * t + 3] = nx2;
    score[t] = sbest;
    cls[t]   = cbest;

    bool valid = (cbest > 0) && (sbest >= MINCONF);
    float ks = valid ? sbest : -1.0f;
    keys[t] = ((unsigned long long)ford(ks) << 32) |
              (unsigned long long)(0xFFFFFFFFu - (uint32_t)i);
}

// ---------------- Kernel 2: per-batch bitonic sort (desc), V, sorted boxes --
__global__ void __launch_bounds__(1024, 1)
k_sort(const unsigned long long* __restrict__ keys,
       const float* __restrict__ refined,
       const int* __restrict__ cls,
       uint32_t* __restrict__ sidx,
       float* __restrict__ sbox,
       int* __restrict__ Vout) {
    __shared__ unsigned long long sk[NPAD];
    __shared__ int sV;
    int b = blockIdx.x, tid = threadIdx.x;

    const unsigned long long* kb = keys + (size_t)b * Nn;
    for (int t = tid; t < NPAD; t += 1024)
        sk[t] = (t < Nn) ? kb[t] : 0ull;      // pads sort to the very end
    if (tid == 0) sV = 0;
    __syncthreads();

    for (int k = 2; k <= NPAD; k <<= 1) {
        for (int j = k >> 1; j > 0; j >>= 1) {
            for (int t = tid; t < NPAD; t += 1024) {
                int ixj = t ^ j;
                if (ixj > t) {
                    unsigned long long a = sk[t], c = sk[ixj];
                    bool desc = ((t & k) == 0);
                    if (desc ? (a < c) : (a > c)) { sk[t] = c; sk[ixj] = a; }
                }
            }
            __syncthreads();
        }
    }

    // valid entries (top bit set: score>=0.7>0) form a prefix; find its length
    for (int t = tid; t < Nn; t += 1024) {
        bool v0 = (sk[t] >> 63) != 0ull;
        bool v1 = (t + 1 < Nn) ? ((sk[t + 1] >> 63) != 0ull) : false;
        if (v0 && !v1) sV = t + 1;            // single boundary -> single writer
    }
    __syncthreads();
    if (tid == 0) Vout[b] = sV;

    for (int t = tid; t < Nn; t += 1024) {
        uint32_t oi = 0xFFFFFFFFu - (uint32_t)(sk[t] & 0xFFFFFFFFull);
        sidx[b * Nn + t] = oi;
        int gi = b * Nn + (int)oi;
        float off = 4.0f * (float)cls[gi];    // CLASS_OFFSET * class_id
        sbox[(size_t)(b * Nn + t) * 4 + 0] = refined[gi * 4 + 0] + off;
        sbox[(size_t)(b * Nn + t) * 4 + 1] = refined[gi * 4 + 1] + off;
        sbox[(size_t)(b * Nn + t) * 4 + 2] = refined[gi * 4 + 2] + off;
        sbox[(size_t)(b * Nn + t) * 4 + 3] = refined[gi * 4 + 3] + off;
    }
}

// ---------------- Kernel 3: IoU suppression bitmask rows, one wave per row --
__global__ void k_iou(const float* __restrict__ sbox,
                      const int* __restrict__ Vbuf,
                      unsigned long long* __restrict__ mask) {
    int gt   = blockIdx.x * blockDim.x + threadIdx.x;
    int wid  = gt >> 6;
    int lane = threadIdx.x & 63;
    if (wid >= Bn * Nn) return;
    int b = wid / Nn, i = wid - b * Nn;
    int V = Vbuf[b];
    if (i >= V) return;

    const float* bb = sbox + (size_t)(b * Nn + i) * 4;
    float y1 = bb[0], x1 = bb[1], y2 = bb[2], x2 = bb[3];
    float ar = (y2 - y1) * (x2 - x1);

    unsigned long long* row = mask + ((size_t)(b * Nn) + (size_t)i) * NW;
    int w0 = i >> 6, wlast = (V - 1) >> 6;
    for (int w = w0; w <= wlast; ++w) {
        int j = (w << 6) + lane;
        bool sup = false;
        if (j > i && j < V) {
            const float* cb = sbox + (size_t)(b * Nn + j) * 4;
            float oy1 = cb[0], ox1 = cb[1], oy2 = cb[2], ox2 = cb[3];
            float a2 = (oy2 - oy1) * (ox2 - ox1);
            float iy = fmaxf(0.0f, fminf(y2, oy2) - fmaxf(y1, oy1));
            float ix = fmaxf(0.0f, fminf(x2, ox2) - fmaxf(x1, ox1));
            float inter = iy * ix;
            float iou = inter / (ar + a2 - inter + 1e-12f);
            sup = iou > NMSTHR;
        }
        unsigned long long ball = __ballot(sup);
        if (lane == 0) row[w] = ball;
    }
}

// ---------------- Kernel 3b: intra-block suppression COLUMNS ----------------
// colG[b*Nn + j] bit i set  <=>  i in j's 64-block, i < j (local), IoU > thr.
__global__ void k_col(const float* __restrict__ sbox,
                      const int* __restrict__ Vbuf,
                      unsigned long long* __restrict__ colG) {
    int gt   = blockIdx.x * blockDim.x + threadIdx.x;
    int wid  = gt >> 6;
    int lane = threadIdx.x & 63;
    if (wid >= Bn * Nn) return;
    int b = wid / Nn, j = wid - b * Nn;
    int V = Vbuf[b];
    if (j >= V) return;

    int jl   = j & 63;
    int base = j - jl;

    const float* bb = sbox + (size_t)(b * Nn + j) * 4;
    float y1 = bb[0], x1 = bb[1], y2 = bb[2], x2 = bb[3];
    float ar = (y2 - y1) * (x2 - x1);

    bool sup = false;
    if (lane < jl) {                           // i < j within block (i < V holds)
        int i = base + lane;
        const float* cb = sbox + (size_t)(b * Nn + i) * 4;
        float oy1 = cb[0], ox1 = cb[1], oy2 = cb[2], ox2 = cb[3];
        float a2 = (oy2 - oy1) * (ox2 - ox1);
        float iy = fmaxf(0.0f, fminf(y2, oy2) - fmaxf(y1, oy1));
        float ix = fmaxf(0.0f, fminf(x2, ox2) - fmaxf(x1, ox1));
        float inter = iy * ix;
        float iou = inter / (ar + a2 - inter + 1e-12f);
        sup = iou > NMSTHR;
    }
    unsigned long long ball = __ballot(sup);
    if (lane == 0) colG[b * Nn + j] = ball;
}

// ---------------- Kernel 4: blockwise greedy scan + parallel emit -----------
// Output == first min(100, nkept) kept boxes in sorted order (per-class cap is
// provably inactive: rank[k] <= k < 100 for the first 100 kept).
__global__ void __launch_bounds__(64, 1)
k_scan(const unsigned long long* __restrict__ mask,
       const unsigned long long* __restrict__ colG,
       const int* __restrict__ Vbuf,
       const uint32_t* __restrict__ sidx,
       const float* __restrict__ refined,
       const float* __restrict__ score,
       const int* __restrict__ cls,
       float* __restrict__ out) {
    int b = blockIdx.x, lane = threadIdx.x;   // 64 threads = 1 wave
    __shared__ int klist[256];                // kept sorted positions (<=163)

    int V = Vbuf[b];
    int nblocks = (V + 63) >> 6;
    int nkept = 0;                            // uniform register

    const unsigned long long* colB  = colG + (size_t)b * Nn;
    const unsigned long long* maskB = mask + (size_t)b * (size_t)Nn * NW;
    const uint32_t*           sidxB = sidx + (size_t)b * Nn;

    unsigned long long col_next = (lane < V) ? colB[lane] : 0ull;

    for (int t = 0; t < nblocks; ++t) {
        unsigned long long col = col_next;
        if (t + 1 < nblocks) {                // prefetch next block's columns
            int j = (t + 1) * 64 + lane;
            col_next = (j < V) ? colB[j] : 0ull;
        }

        // rm word t = OR over all kept rows' word t (lanes gather, then reduce)
        unsigned long long rm = 0ull;
        for (int k = lane; k < nkept; k += 64)
            rm |= maskB[(size_t)klist[k] * NW + t];
        #pragma unroll
        for (int m = 32; m >= 1; m >>= 1)
            rm |= __shfl_xor(rm, m, 64);

        int nb = V - t * 64; if (nb > 64) nb = 64;
        bool alive = (lane < nb) && !((rm >> lane) & 1ull);
        unsigned long long cand = __ballot(alive);
        unsigned long long keepw = 0ull;
        while (cand) {                         // one iteration per KEPT box
            int i = __builtin_ctzll(cand);
            keepw |= (1ull << i);
            alive = alive && !((col >> i) & 1ull);   // self-removal via column bit
            cand = __ballot(alive) & ~((2ull << i) - 1ull);
        }

        // append kept positions (uniform scalar loop; lane0 writes LDS)
        unsigned long long kk = keepw;
        while (kk) {
            int i = __builtin_ctzll(kk);
            kk &= kk - 1;
            if (lane == 0) klist[nkept] = t * 64 + i;
            ++nkept;
        }
        __syncthreads();
        if (nkept >= MAXI) break;             // output fully determined
    }

    int ne = nkept < MAXI ? nkept : MAXI;
    for (int r = lane; r < ne; r += 64) {     // parallel emit
        int gi = b * Nn + (int)sidxB[klist[r]];
        float* orow = out + ((size_t)b * MAXI + r) * 6;
        orow[0] = refined[gi * 4 + 0];
        orow[1] = refined[gi * 4 + 1];
        orow[2] = refined[gi * 4 + 2];
        orow[3] = refined[gi * 4 + 3];
        orow[4] = (float)cls[gi];
        orow[5] = score[gi];
    }
    for (int tt = ne * 6 + lane; tt < MAXI * 6; tt += 64)
        out[(size_t)b * MAXI * 6 + tt] = 0.0f;
}

// ---------------- launch ----------------------------------------------------
extern "C" void kernel_launch(void* const* d_in, const int* in_sizes, int n_in,
                              void* d_out, int out_size, void* d_ws, size_t ws_size,
                              hipStream_t stream) {
    const float* rois  = (const float*)d_in[0];
    const float* probs = (const float*)d_in[1];
    const float* bbox  = (const float*)d_in[2];
    const float* meta  = (const float*)d_in[3];
    float* out = (float*)d_out;

    const int BN = Bn * Nn;
    char* ws = (char*)d_ws;
    size_t off = 0;
    auto alloc = [&](size_t bytes) {
        void* p = ws + off;
        off += (bytes + 255) & ~(size_t)255;
        return p;
    };
    float*              refined = (float*)              alloc((size_t)BN * 4 * sizeof(float));
    float*              score   = (float*)              alloc((size_t)BN * sizeof(float));
    int*                cls     = (int*)                alloc((size_t)BN * sizeof(int));
    unsigned long long* keys    = (unsigned long long*) alloc((size_t)BN * sizeof(unsigned long long));
    uint32_t*           sidx    = (uint32_t*)           alloc((size_t)BN * sizeof(uint32_t));
    float*              sbox    = (float*)              alloc((size_t)BN * 4 * sizeof(float));
    int*                Vbuf    = (int*)                alloc((size_t)Bn * sizeof(int));
    unsigned long long* colG    = (unsigned long long*) alloc((size_t)BN * sizeof(unsigned long long));
    unsigned long long* mask    = (unsigned long long*) alloc((size_t)BN * NW * sizeof(unsigned long long));
    (void)ws_size; (void)in_sizes; (void)n_in; (void)out_size;

    k_prep<<<(BN + 255) / 256, 256, 0, stream>>>(rois, probs, bbox, meta,
                                                 refined, score, cls, keys);
    k_sort<<<Bn, 1024, 0, stream>>>(keys, refined, cls, sidx, sbox, Vbuf);
    k_iou<<<(BN * 64 + 255) / 256, 256, 0, stream>>>(sbox, Vbuf, mask);
    k_col<<<(BN * 64 + 255) / 256, 256, 0, stream>>>(sbox, Vbuf, colG);
    k_scan<<<Bn, 64, 0, stream>>>(mask, colG, Vbuf, sidx, refined, score, cls, out);
}